// Round 1
// baseline (935.651 us; speedup 1.0000x reference)
//
#include <hip/hip_runtime.h>

#define CC 256          // channels
#define GG 1024         // graphs
#define RR 16           // bottleneck dim (C/R)
#define ROWS_PER_BLOCK 256

// ---------------- Kernel 1: segment sum + counts (sorted batch_idx) --------
// Block = 256 threads = 4 waves. Wave w handles rows base+w, base+w+4, ...
// Lane l holds channels [4l, 4l+4) as a float4 register accumulator.
// Flush to global atomics only when the graph id changes (sorted input) or
// at the end of the chunk -> ~2M atomics instead of 128M.
__global__ void seg_sum_kernel(const float* __restrict__ x,
                               const int* __restrict__ batch_idx,
                               float* __restrict__ seg,
                               float* __restrict__ cnt,
                               int n) {
    const int wave = threadIdx.x >> 6;
    const int lane = threadIdx.x & 63;
    const int base = blockIdx.x * ROWS_PER_BLOCK;
    const int rend = min(base + ROWS_PER_BLOCK, n);

    float4 acc = make_float4(0.f, 0.f, 0.f, 0.f);
    int cur_g = -1;
    int cl = 0;

    for (int row = base + wave; row < rend; row += 4) {
        const int g = batch_idx[row];          // wave-uniform (all lanes same row)
        if (g != cur_g) {                      // wave-uniform branch
            if (cur_g >= 0) {
                float* p = seg + (size_t)cur_g * CC + lane * 4;
                atomicAdd(p + 0, acc.x);
                atomicAdd(p + 1, acc.y);
                atomicAdd(p + 2, acc.z);
                atomicAdd(p + 3, acc.w);
                if (lane == 0) atomicAdd(cnt + cur_g, (float)cl);
            }
            cur_g = g;
            acc = make_float4(0.f, 0.f, 0.f, 0.f);
            cl = 0;
        }
        const float4 v =
            *reinterpret_cast<const float4*>(x + (size_t)row * CC + lane * 4);
        acc.x += v.x; acc.y += v.y; acc.z += v.z; acc.w += v.w;
        ++cl;
    }
    if (cur_g >= 0) {
        float* p = seg + (size_t)cur_g * CC + lane * 4;
        atomicAdd(p + 0, acc.x);
        atomicAdd(p + 1, acc.y);
        atomicAdd(p + 2, acc.z);
        atomicAdd(p + 3, acc.w);
        if (lane == 0) atomicAdd(cnt + cur_g, (float)cl);
    }
}

// ---------------- Kernel 2: mean + Linear(256->16) + PReLU + Linear(16->256)
//                  + sigmoid. One block (256 thr) per graph. Tiny. ----------
__global__ void mlp_kernel(const float* __restrict__ seg,
                           const float* __restrict__ cnt,
                           const float* __restrict__ W1,
                           const float* __restrict__ prelu_a,
                           const float* __restrict__ W2,
                           float* __restrict__ score) {
    __shared__ float xm[CC];
    __shared__ float h[RR];
    const int g = blockIdx.x;
    const int t = threadIdx.x;

    const float c   = cnt[g];
    const float inv = 1.0f / fmaxf(c, 1.0f);
    xm[t] = seg[(size_t)g * CC + t] * inv;
    __syncthreads();

    if (t < RR) {
        const float a = *prelu_a;
        float acc = 0.f;
        const float* w = W1 + t * CC;      // W1[r, c] row-major, 'gc,rc->gr'
        #pragma unroll 8
        for (int cc2 = 0; cc2 < CC; ++cc2) acc += xm[cc2] * w[cc2];
        h[t] = (acc >= 0.f) ? acc : a * acc;   // PReLU, scalar a
    }
    __syncthreads();

    float acc2 = 0.f;
    const float* w2 = W2 + t * RR;         // W2[c, r] row-major, 'gr,cr->gc'
    #pragma unroll
    for (int r = 0; r < RR; ++r) acc2 += h[r] * w2[r];
    score[(size_t)g * CC + t] = 1.0f / (1.0f + __expf(-acc2));
}

// ---------------- Kernel 3: out = x * score[batch_idx], float4 lanes -------
// Lanes of one wave cover exactly one row (64 * float4 = 256 ch): batch_idx
// load is wave-uniform, score row read is a coalesced 1 KiB L2 hit.
__global__ void apply_kernel(const float4* __restrict__ x4,
                             const int* __restrict__ batch_idx,
                             const float4* __restrict__ score4,
                             float4* __restrict__ out4,
                             long total) {
    const long i = (long)blockIdx.x * blockDim.x + threadIdx.x;
    if (i >= total) return;
    const int row = (int)(i >> 6);
    const int c4  = (int)(i & 63);
    const int g   = batch_idx[row];
    const float4 v = x4[i];
    const float4 s = score4[(size_t)g * 64 + c4];
    out4[i] = make_float4(v.x * s.x, v.y * s.y, v.z * s.z, v.w * s.w);
}

extern "C" void kernel_launch(void* const* d_in, const int* in_sizes, int n_in,
                              void* d_out, int out_size, void* d_ws, size_t ws_size,
                              hipStream_t stream) {
    // inputs: 0=x [N*C f32], 1=batch_idx [N i32], 2=num_graphs (i32 scalar),
    //         3=W1 [16*256 f32], 4=prelu_a (f32 scalar), 5=W2 [256*16 f32]
    const float* x    = (const float*)d_in[0];
    const int*   bidx = (const int*)d_in[1];
    const float* W1   = (const float*)d_in[3];
    const float* pa   = (const float*)d_in[4];
    const float* W2   = (const float*)d_in[5];
    float*       out  = (float*)d_out;

    const int n = in_sizes[1];                 // N = 500000

    float* seg   = (float*)d_ws;               // [G, C]   = 1 MB
    float* cnt   = seg + (size_t)GG * CC;      // [G]      = 4 KB
    float* score = cnt + GG;                   // [G, C]   = 1 MB

    // ws is poisoned 0xAA before every launch: zero the accumulators.
    hipMemsetAsync(d_ws, 0, ((size_t)GG * CC + GG) * sizeof(float), stream);

    const int nb1 = (n + ROWS_PER_BLOCK - 1) / ROWS_PER_BLOCK;
    seg_sum_kernel<<<nb1, 256, 0, stream>>>(x, bidx, seg, cnt, n);

    mlp_kernel<<<GG, CC, 0, stream>>>(seg, cnt, W1, pa, W2, score);

    const long total = (long)n * (CC / 4);
    const int nb3 = (int)((total + 255) / 256);
    apply_kernel<<<nb3, 256, 0, stream>>>((const float4*)x, bidx,
                                          (const float4*)score, (float4*)out,
                                          total);
}